// Round 2
// baseline (933.519 us; speedup 1.0000x reference)
//
#include <hip/hip_runtime.h>
#include <cstdint>
#include <cstddef>

// N=100000, E=300000, B=50000, L=4, D_EMB=128, D_HID=64, H=8. fp32 in/out.
// R5: single persistent mega-kernel with software grid barriers.
// Phases: P0 packW+batch-hist | P1 GEMM(+P)+edge-hist | P2 chunk-reduce |
// P3 scan->offsets/cursor | P4 scatter+logits | P5 node_agg(online softmax)
// | P6 gate-reduce(per block)+output.  Dispatches: 10 -> 2 (memset + mega).
// Co-residency: __launch_bounds__(256,4) + occupancy query, grid <= 1024.

typedef __attribute__((ext_vector_type(8))) short bf16x8;
typedef __attribute__((ext_vector_type(4))) float f32x4;

__device__ __forceinline__ unsigned short f2bf(float f) {
    unsigned u = __float_as_uint(f);
    unsigned r = u + 0x7fffu + ((u >> 16) & 1u);
    return (unsigned short)(r >> 16);
}
__device__ __forceinline__ float bf2f(unsigned short h) {
    return __uint_as_float((unsigned)h << 16);
}

// Sense-reversal grid barrier. Safe: barrier k cannot complete until every
// block arrives, so a block's pre-arrival read of gen is always the current
// generation. Last block resets counter (relaxed) before releasing gen;
// waiters acquire gen -> transitively see all pre-barrier stores.
__device__ __forceinline__ void gsync(unsigned* cnt, unsigned* gen, unsigned nb) {
    __syncthreads();
    if (threadIdx.x == 0) {
        unsigned g = __hip_atomic_load(gen, __ATOMIC_RELAXED, __HIP_MEMORY_SCOPE_AGENT);
        unsigned arrived = __hip_atomic_fetch_add(cnt, 1u, __ATOMIC_ACQ_REL,
                                                  __HIP_MEMORY_SCOPE_AGENT);
        if (arrived == nb - 1u) {
            __hip_atomic_store(cnt, 0u, __ATOMIC_RELAXED, __HIP_MEMORY_SCOPE_AGENT);
            __hip_atomic_store(gen, g + 1u, __ATOMIC_RELEASE, __HIP_MEMORY_SCOPE_AGENT);
        } else {
            while (__hip_atomic_load(gen, __ATOMIC_ACQUIRE,
                                     __HIP_MEMORY_SCOPE_AGENT) == g)
                __builtin_amdgcn_s_sleep(1);
        }
    }
    __syncthreads();
}

__global__ __launch_bounds__(256, 4) void k_mega(
    const int* __restrict__ batch_nodes, const int* __restrict__ mp,
    const int* __restrict__ edge_dst, const float* __restrict__ feat,
    const float* __restrict__ Wi, const float* __restrict__ Wp,
    const float* __restrict__ attn, const float* __restrict__ Wth,
    const float* __restrict__ Wg, const float* __restrict__ bg,
    float* __restrict__ out,
    unsigned short* __restrict__ Whi, unsigned short* __restrict__ Wlo,
    unsigned short* __restrict__ Ybf, float* __restrict__ P,
    float* __restrict__ logits, int4* __restrict__ mpc,
    int* __restrict__ mult, int* __restrict__ count,
    float* __restrict__ gate_part, int* __restrict__ offsets,
    int* __restrict__ cursor, int* __restrict__ partials,
    unsigned short* __restrict__ nftb, unsigned* __restrict__ bar,
    int N, int E, int B, int nb) {

    __shared__ union {
        struct { unsigned short h[4096]; unsigned short l[4096]; } stage; // 16KB
        int   scan[256];
        float fred[256];
    } sm;
    __shared__ float sgate[8];

    const int bid = blockIdx.x, tid = threadIdx.x;
    const int gtid = bid * 256 + tid;
    const int nthreads = nb * 256;
    unsigned* cnt = bar;
    unsigned* gen = bar + 1;

    // ---- P0: pack W = [Wi;Wp].T into MFMA B-frag order (split hi/lo bf16)
    //          + batch-node multiplicity histogram
    for (int t = gtid; t < 16384; t += nthreads) {
        int j = t & 7, L = (t >> 3) & 63, c = (t >> 9) & 7, s = t >> 12;
        int k = s * 32 + (L >> 4) * 8 + j;
        int n = c * 16 + (L & 15);
        float v = (n < 64) ? Wi[n * 128 + k] : Wp[(n - 64) * 128 + k];
        unsigned short h = f2bf(v);
        Whi[t] = h;
        Wlo[t] = f2bf(v - bf2f(h));
    }
    for (int i = gtid; i < B; i += nthreads)
        atomicAdd(&mult[batch_nodes[i]], 1);
    gsync(cnt, gen, nb);

    // ---- P1: edge histogram (needs mult) + dense GEMM Ybf = feat @ Wpack
    for (int e = gtid; e < E; e += nthreads) {
        int d = edge_dst[e];
        if (mult[d] > 0) atomicAdd(&count[d], 1);
    }
    {
        const int wave = tid >> 6;
        const int L = tid & 63;
        const int m = L & 15, q = L >> 4;
        const int ntiles = (N + 63) >> 6;
        for (int tile = bid; tile < ntiles; tile += nb) {
            int R0 = tile * 64 + wave * 16;
            f32x4 acc[8];
#pragma unroll
            for (int c = 0; c < 8; ++c) acc[c] = (f32x4){0.f, 0.f, 0.f, 0.f};
            int rowc = R0 + m; if (rowc > N - 1) rowc = N - 1;
            const float* arow = feat + (size_t)rowc * 128;

            for (int s = 0; s < 4; ++s) {
                __syncthreads();   // protect previous LDS reads
                {
                    bf16x8* shp = (bf16x8*)sm.stage.h;
                    bf16x8* slp = (bf16x8*)sm.stage.l;
                    const bf16x8* gh = (const bf16x8*)(Whi + s * 4096);
                    const bf16x8* gl = (const bf16x8*)(Wlo + s * 4096);
                    shp[tid] = gh[tid]; shp[tid + 256] = gh[tid + 256];
                    slp[tid] = gl[tid]; slp[tid + 256] = gl[tid + 256];
                }
                __syncthreads();

                const float4* ap = (const float4*)(arow + s * 32 + q * 8);
                float4 a0 = ap[0], a1 = ap[1];
                float av[8] = {a0.x, a0.y, a0.z, a0.w, a1.x, a1.y, a1.z, a1.w};
                bf16x8 ahi, alo;
#pragma unroll
                for (int j = 0; j < 8; ++j) {
                    unsigned short h = f2bf(av[j]);
                    ahi[j] = (short)h;
                    alo[j] = (short)f2bf(av[j] - bf2f(h));
                }
#pragma unroll
                for (int c = 0; c < 8; ++c) {
                    const bf16x8 bh = *(const bf16x8*)(sm.stage.h + c * 512 + L * 8);
                    const bf16x8 bl = *(const bf16x8*)(sm.stage.l + c * 512 + L * 8);
                    acc[c] = __builtin_amdgcn_mfma_f32_16x16x32_bf16(ahi, bh, acc[c], 0, 0, 0);
                    acc[c] = __builtin_amdgcn_mfma_f32_16x16x32_bf16(ahi, bl, acc[c], 0, 0, 0);
                    acc[c] = __builtin_amdgcn_mfma_f32_16x16x32_bf16(alo, bh, acc[c], 0, 0, 0);
                }
            }
            // C/D layout: col = lane&15 (=m), row = (lane>>4)*4 + reg (=q*4+r)
#pragma unroll
            for (int c = 0; c < 8; ++c) {
#pragma unroll
                for (int r = 0; r < 4; ++r) {
                    int row = R0 + q * 4 + r;
                    if (row < N) Ybf[(size_t)row * 128 + c * 16 + m] = f2bf(acc[c][r]);
                }
            }
            // P epilogue: P[row,i]=Yi[row].attn_i, P[row,8+i]=Yp[row].attn_i
#pragma unroll
            for (int i = 0; i < 8; ++i) {
                float a0 = attn[i * 64 + m];
                float a1 = attn[i * 64 + 16 + m];
                float a2 = attn[i * 64 + 32 + m];
                float a3 = attn[i * 64 + 48 + m];
#pragma unroll
                for (int r = 0; r < 4; ++r) {
                    int row = R0 + q * 4 + r;
                    float pi = acc[0][r] * a0 + acc[1][r] * a1 + acc[2][r] * a2 + acc[3][r] * a3;
                    float pp = acc[4][r] * a0 + acc[5][r] * a1 + acc[6][r] * a2 + acc[7][r] * a3;
#pragma unroll
                    for (int o = 1; o < 16; o <<= 1) {
                        pi += __shfl_xor(pi, o);
                        pp += __shfl_xor(pp, o);
                    }
                    if (row < N) {
                        if (m == i)     P[(size_t)row * 16 + i] = pi;
                        if (m == i + 8) P[(size_t)row * 16 + 8 + i] = pp;
                    }
                }
            }
        }
    }
    gsync(cnt, gen, nb);

    // ---- P2: per-256-chunk reduction of count -> partials
    const int nchunks = (N + 255) >> 8;
    for (int chunk = bid; chunk < nchunks; chunk += nb) {
        int i = chunk * 256 + tid;
        int c = (i < N) ? count[i] : 0;
        sm.scan[tid] = c; __syncthreads();
#pragma unroll
        for (int o = 128; o > 0; o >>= 1) {
            if (tid < o) sm.scan[tid] += sm.scan[tid + o];
            __syncthreads();
        }
        if (tid == 0) partials[chunk] = sm.scan[0];
        __syncthreads();
    }
    gsync(cnt, gen, nb);

    // ---- P3: chunk offset (sum partials<chunk) + intra-chunk scan -> offsets/cursor
    for (int chunk = bid; chunk < nchunks; chunk += nb) {
        int s = 0;
        for (int j = tid; j < chunk; j += 256) s += partials[j];
        sm.scan[tid] = s; __syncthreads();
#pragma unroll
        for (int o = 128; o > 0; o >>= 1) {
            if (tid < o) sm.scan[tid] += sm.scan[tid + o];
            __syncthreads();
        }
        int boff = sm.scan[0]; __syncthreads();
        int i = chunk * 256 + tid;
        int c = (i < N) ? count[i] : 0;
        sm.scan[tid] = c; __syncthreads();
        for (int o = 1; o < 256; o <<= 1) {
            int v = (tid >= o) ? sm.scan[tid - o] : 0;
            __syncthreads(); sm.scan[tid] += v; __syncthreads();
        }
        int off = boff + sm.scan[tid] - c;
        if (i < N) { offsets[i] = off; cursor[i] = off; }
        if (tid == 255 && chunk == nchunks - 1) offsets[N] = boff + sm.scan[255];
        __syncthreads();
    }
    gsync(cnt, gen, nb);

    // ---- P4: fused scatter + talking-heads logits (8 lanes/edge)
    {
        int grp = tid >> 3;
        int h = tid & 7;
        int gbase = tid & ~7;
        for (int e = bid * 32 + grp; e < E; e += nb * 32) {
            int d = edge_dst[e];
            if (mult[d] == 0) continue;
            int pos = 0;
            if (h == 0) pos = atomicAdd(&cursor[d], 1);
            pos = __shfl(pos, gbase);
            int4 rows = *(const int4*)(mp + (size_t)e * 4);
            float s = P[(size_t)rows.x * 16 + h] + P[(size_t)rows.w * 16 + h]
                    + P[(size_t)rows.y * 16 + 8 + h] + P[(size_t)rows.z * 16 + 8 + h];
            float l = 0.f;
#pragma unroll
            for (int j = 0; j < 8; ++j) {
                float sj = __shfl(s, gbase + j);
                l += Wth[h * 8 + j] * sj;
            }
            l = l > 0.f ? l : 0.01f * l;
            logits[(size_t)pos * 8 + h] = l;
            if (h == 0) mpc[pos] = rows;
        }
    }
    gsync(cnt, gen, nb);

    // ---- P5: per flagged node online softmax + aggregation + gate partials
    {
        int lane = tid & 63;
        int gwave = bid * 4 + (tid >> 6);
        float wg = Wg[lane];
        for (int n = gwave; n < N; n += nb * 4) {
            int mlt = mult[n];
            if (mlt == 0) continue;
            int beg = offsets[n], end = offsets[n + 1];

            float mx[8], den[8], acc[8];
#pragma unroll
            for (int h = 0; h < 8; ++h) { mx[h] = -1e30f; den[h] = 0.f; acc[h] = 0.f; }

            for (int j = beg; j < end; ++j) {
                const float4* lp = (const float4*)(logits + (size_t)j * 8);
                float4 l0 = lp[0], l1 = lp[1];
                int4 rows = mpc[j];
                float ed = bf2f(Ybf[(size_t)rows.x * 128 + lane])
                         + bf2f(Ybf[(size_t)rows.w * 128 + lane])
                         + bf2f(Ybf[(size_t)rows.y * 128 + 64 + lane])
                         + bf2f(Ybf[(size_t)rows.z * 128 + 64 + lane]);
#define OSM_STEP(H, LV)                                            \
                {                                                  \
                    float nm = fmaxf(mx[H], (LV));                 \
                    float cr = __expf(mx[H] - nm);                 \
                    float w  = __expf((LV) - nm);                  \
                    den[H] = den[H] * cr + w;                      \
                    acc[H] = acc[H] * cr + w * ed;                 \
                    mx[H] = nm;                                    \
                }
                OSM_STEP(0, l0.x) OSM_STEP(1, l0.y) OSM_STEP(2, l0.z) OSM_STEP(3, l0.w)
                OSM_STEP(4, l1.x) OSM_STEP(5, l1.y) OSM_STEP(6, l1.z) OSM_STEP(7, l1.w)
#undef OSM_STEP
            }
#pragma unroll
            for (int h = 0; h < 8; ++h) {
                float r = (end > beg) ? 1.f / den[h] : 0.f;
                acc[h] *= r;
            }

            unsigned short* base = nftb + (size_t)n * 512;
#pragma unroll
            for (int h = 0; h < 8; ++h) base[h * 64 + lane] = f2bf(acc[h]);

            float myg = 0.f;
#pragma unroll
            for (int h = 0; h < 8; ++h) {
                float p = acc[h] * wg;
#pragma unroll
                for (int o = 32; o > 0; o >>= 1) p += __shfl_xor(p, o);
                if (lane == h) myg = p;
            }
            if (lane < 8)
                atomicAdd(&gate_part[bid * 8 + lane], (float)mlt * myg);
        }
    }
    gsync(cnt, gen, nb);

    // ---- P6: per-block (redundant) gate reduction, then gated output gather
    {
        int hh = tid & 7, g = tid >> 3;
        float s = 0.f;
        for (int b = g; b < 1024; b += 32) s += gate_part[b * 8 + hh];
        sm.fred[tid] = s; __syncthreads();
        if (tid < 8) {
            float tot = 0.f;
            for (int gg = 0; gg < 32; ++gg) tot += sm.fred[gg * 8 + tid];
            sgate[tid] = tot / (float)B + bg[0];
        }
        __syncthreads();
    }
    {
        int total = B * 128;
        for (int idx = gtid; idx < total; idx += nthreads) {
            int b = idx >> 7;
            int rem = idx & 127;
            int hh = rem >> 4;
            int n = batch_nodes[b];
            ushort4 v = *(const ushort4*)(nftb + (size_t)n * 512 + rem * 4);
            float g = sgate[hh];
            float4 o;
            o.x = bf2f(v.x) * g; o.y = bf2f(v.y) * g;
            o.z = bf2f(v.z) * g; o.w = bf2f(v.w) * g;
            *(float4*)(out + (size_t)idx * 4) = o;
        }
    }
}

// ---------------------------------------------------------------------------
extern "C" void kernel_launch(void* const* d_in, const int* in_sizes, int n_in,
                              void* d_out, int out_size, void* d_ws, size_t ws_size,
                              hipStream_t stream) {
    const int*   batch_nodes = (const int*)d_in[0];
    const int*   mp          = (const int*)d_in[1];
    const int*   edge_dst    = (const int*)d_in[2];
    const float* feat        = (const float*)d_in[3];
    const float* W_i         = (const float*)d_in[4];
    const float* W_p         = (const float*)d_in[5];
    const float* attn        = (const float*)d_in[6];
    const float* W_th        = (const float*)d_in[7];
    const float* W_gate      = (const float*)d_in[8];
    const float* b_gate      = (const float*)d_in[9];
    float* out = (float*)d_out;

    const int B = in_sizes[0];
    const int E = in_sizes[2];
    const int N = in_sizes[3] / 128;

    char* w = (char*)d_ws;
    auto alloc = [&](size_t bytes) -> void* {
        void* p = (void*)w;
        w += (bytes + 255) & ~(size_t)255;
        return p;
    };
    unsigned short* Whi = (unsigned short*)alloc(16384 * 2);
    unsigned short* Wlo = (unsigned short*)alloc(16384 * 2);
    unsigned short* Ybf = (unsigned short*)alloc((size_t)N * 128 * 2);   // 25.6 MB
    float* P            = (float*)alloc((size_t)N * 16 * 4);             // 6.4 MB
    float* logits       = (float*)alloc((size_t)E * 8 * 4);              // 9.6 MB
    int4*  mpc          = (int4*)alloc((size_t)E * 16);                  // 4.8 MB
    // contiguous zero region: mult | count | gate_part | bar
    size_t zero_ints    = (size_t)2 * N + 8192 + 16;
    int*   mult         = (int*)alloc(zero_ints * 4);
    int*   count        = mult + N;
    float* gate_part    = (float*)(count + N);
    unsigned* bar       = (unsigned*)(gate_part + 8192);
    int*   offsets      = (int*)alloc((size_t)(N + 1) * 4);
    int*   cursor       = (int*)alloc((size_t)N * 4);
    int*   partials     = (int*)alloc(512 * 4);
    unsigned short* nftb = (unsigned short*)alloc((size_t)N * 512 * 2);  // 102.4 MB

    static int nb_cached = 0;
    if (nb_cached == 0) {
        int occ = 0;
        hipError_t err = hipOccupancyMaxActiveBlocksPerMultiprocessor(
            &occ, reinterpret_cast<const void*>(k_mega), 256, 0);
        if (err != hipSuccess || occ < 1) occ = 1;
        hipDeviceProp_t prop;
        int mpc_count = 256;
        if (hipGetDeviceProperties(&prop, 0) == hipSuccess)
            mpc_count = prop.multiProcessorCount;
        long nb = (long)occ * mpc_count;
        if (nb > 1024) nb = 1024;
        if (nb < 1) nb = 1;
        nb_cached = (int)nb;
    }
    const int nb = nb_cached;

    hipMemsetAsync(mult, 0, zero_ints * 4, stream);
    k_mega<<<nb, 256, 0, stream>>>(batch_nodes, mp, edge_dst, feat, W_i, W_p,
                                   attn, W_th, W_gate, b_gate, out,
                                   Whi, Wlo, Ybf, P, logits, mpc,
                                   mult, count, gate_part, offsets, cursor,
                                   partials, nftb, bar, N, E, B, nb);
}

// Round 4
// 333.880 us; speedup vs baseline: 2.7960x; 2.7960x over previous
//
#include <hip/hip_runtime.h>
#include <cstdint>
#include <cstddef>

// N=100000, E=300000, B=50000, L=4, D_EMB=128, D_HID=64, H=8. fp32 in/out.
// R6b: same as R6, compile fix: nontemporal stores via clang ext_vector
// float4 (HIP_vector_type float4 is a struct, rejected by the builtin).
//  - edge-hist folded into k_dense prologue (-1 dispatch, hides under GEMM)
//  - k_node_agg 2-edge unroll (overlap L3 gather latency)
//  - k_output ushort8 (16B/lane) + nontemporal 16B stores
// Dispatches: 9 (memset, prep, dense, scan1, scan23, scatter_logits,
//                node_agg, gatefinal, output).

typedef __attribute__((ext_vector_type(8))) short bf16x8;
typedef __attribute__((ext_vector_type(4))) float f32x4;
typedef __attribute__((ext_vector_type(8))) unsigned short u16x8;

__device__ __forceinline__ unsigned short f2bf(float f) {
    unsigned u = __float_as_uint(f);
    unsigned r = u + 0x7fffu + ((u >> 16) & 1u);
    return (unsigned short)(r >> 16);
}
__device__ __forceinline__ float bf2f(unsigned short h) {
    return __uint_as_float((unsigned)h << 16);
}

// ---------------------------------------------------------------------------
// Pack B = [Wi;Wp].T (K=128 x N=128) into MFMA B-frag order, split hi/lo bf16.
// pack[(s*8+c)*512 + L*8 + j] = B[k][n], k=s*32+(L>>4)*8+j, n=c*16+(L&15).
// Fused: batch-node multiplicity histogram.
__global__ __launch_bounds__(256) void k_prep(
    const float* __restrict__ Wi, const float* __restrict__ Wp,
    unsigned short* __restrict__ Whi, unsigned short* __restrict__ Wlo,
    const int* __restrict__ batch_nodes, int* __restrict__ mult, int B) {
    int t = blockIdx.x * 256 + threadIdx.x;
    if (t < B) atomicAdd(&mult[batch_nodes[t]], 1);
    if (t >= 16384) return;
    int j = t & 7, L = (t >> 3) & 63, c = (t >> 9) & 7, s = t >> 12;
    int k = s * 32 + (L >> 4) * 8 + j;
    int n = c * 16 + (L & 15);
    float v = (n < 64) ? Wi[n * 128 + k] : Wp[(n - 64) * 128 + k];
    unsigned short h = f2bf(v);
    Whi[t] = h;
    Wlo[t] = f2bf(v - bf2f(h));
}

// ---------------------------------------------------------------------------
// Dense GEMM: Ybf[M x 128] = feat[M x 128] @ B, split-bf16 (3 MFMA per tile).
// Prologue: edge histogram (needs mult; k_prep precedes). Hist gathers hide
// under the MFMA/staging work of the same kernel.
// Epilogue: P[n,16] = {Yi[n].attn_i, Yp[n].attn_i} from fp32 acc.
__global__ __launch_bounds__(256) void k_dense(
    const float* __restrict__ feat, const unsigned short* __restrict__ Whi,
    const unsigned short* __restrict__ Wlo, const float* __restrict__ attn,
    const int* __restrict__ edge_dst, const int* __restrict__ mult,
    int* __restrict__ count, unsigned short* __restrict__ Ybf,
    float* __restrict__ P, int M, int E) {
    __shared__ unsigned short sBh[4096];
    __shared__ unsigned short sBl[4096];
    int t = threadIdx.x;

    // edge-hist prologue (grid covers E: (M+63)/64 * 256 >= 390k > 300k)
    {
        int e = blockIdx.x * 256 + t;
        if (e < E) {
            int d = edge_dst[e];
            if (mult[d] > 0) atomicAdd(&count[d], 1);
        }
    }

    int wave = t >> 6;
    int L = t & 63;
    int m = L & 15, q = L >> 4;
    int R0 = blockIdx.x * 64 + wave * 16;

    f32x4 acc[8];
#pragma unroll
    for (int c = 0; c < 8; ++c) acc[c] = (f32x4){0.f, 0.f, 0.f, 0.f};

    int rowc = R0 + m; if (rowc > M - 1) rowc = M - 1;
    const float* arow = feat + (size_t)rowc * 128;

    for (int s = 0; s < 4; ++s) {
        __syncthreads();   // protect previous iteration's LDS reads
        {
            bf16x8* shp = (bf16x8*)sBh;
            bf16x8* slp = (bf16x8*)sBl;
            const bf16x8* gh = (const bf16x8*)(Whi + s * 4096);
            const bf16x8* gl = (const bf16x8*)(Wlo + s * 4096);
            shp[t] = gh[t]; shp[t + 256] = gh[t + 256];
            slp[t] = gl[t]; slp[t + 256] = gl[t + 256];
        }
        __syncthreads();

        const float4* ap = (const float4*)(arow + s * 32 + q * 8);
        float4 a0 = ap[0], a1 = ap[1];
        float av[8] = {a0.x, a0.y, a0.z, a0.w, a1.x, a1.y, a1.z, a1.w};
        bf16x8 ahi, alo;
#pragma unroll
        for (int j = 0; j < 8; ++j) {
            unsigned short h = f2bf(av[j]);
            ahi[j] = (short)h;
            alo[j] = (short)f2bf(av[j] - bf2f(h));
        }
#pragma unroll
        for (int c = 0; c < 8; ++c) {
            const bf16x8 bh = *(const bf16x8*)(sBh + c * 512 + L * 8);
            const bf16x8 bl = *(const bf16x8*)(sBl + c * 512 + L * 8);
            acc[c] = __builtin_amdgcn_mfma_f32_16x16x32_bf16(ahi, bh, acc[c], 0, 0, 0);
            acc[c] = __builtin_amdgcn_mfma_f32_16x16x32_bf16(ahi, bl, acc[c], 0, 0, 0);
            acc[c] = __builtin_amdgcn_mfma_f32_16x16x32_bf16(alo, bh, acc[c], 0, 0, 0);
        }
    }
    // C/D layout: col = lane&15 (=m), row = (lane>>4)*4 + reg (=q*4+r)
#pragma unroll
    for (int c = 0; c < 8; ++c) {
#pragma unroll
        for (int r = 0; r < 4; ++r) {
            int row = R0 + q * 4 + r;
            if (row < M) Ybf[(size_t)row * 128 + c * 16 + m] = f2bf(acc[c][r]);
        }
    }
    // P epilogue: P[row,i] = Yi[row].attn_i, P[row,8+i] = Yp[row].attn_i.
    // Lane (q,m) holds cols c*16+m of rows q*4+r; reduce over m (16-lane group).
#pragma unroll
    for (int i = 0; i < 8; ++i) {
        float a0 = attn[i * 64 + m];
        float a1 = attn[i * 64 + 16 + m];
        float a2 = attn[i * 64 + 32 + m];
        float a3 = attn[i * 64 + 48 + m];
#pragma unroll
        for (int r = 0; r < 4; ++r) {
            int row = R0 + q * 4 + r;
            float pi = acc[0][r] * a0 + acc[1][r] * a1 + acc[2][r] * a2 + acc[3][r] * a3;
            float pp = acc[4][r] * a0 + acc[5][r] * a1 + acc[6][r] * a2 + acc[7][r] * a3;
#pragma unroll
            for (int o = 1; o < 16; o <<= 1) {
                pi += __shfl_xor(pi, o);
                pp += __shfl_xor(pp, o);
            }
            if (row < M) {
                if (m == i)     P[(size_t)row * 16 + i] = pi;
                if (m == i + 8) P[(size_t)row * 16 + 8 + i] = pp;
            }
        }
    }
}

// ---------------------------------------------------------------------------
// per-block exclusive scan of count + block partial sums
__global__ __launch_bounds__(256) void k_scan1(
    const int* __restrict__ count, int* __restrict__ excl, int* __restrict__ partials, int N) {
    __shared__ int lds[256];
    int t = threadIdx.x, i = blockIdx.x * 256 + t;
    int c = (i < N) ? count[i] : 0;
    lds[t] = c; __syncthreads();
    for (int o = 1; o < 256; o <<= 1) {
        int v = (t >= o) ? lds[t - o] : 0;
        __syncthreads(); lds[t] += v; __syncthreads();
    }
    if (i < N) excl[i] = lds[t] - c;
    if (t == 255) partials[blockIdx.x] = lds[255];
}

// merged scan2+scan3: each block reduces partials[0..bid) itself (<=512 ints),
// then writes offsets/cursor; last block also writes offsets[N] = Ec.
__global__ __launch_bounds__(256) void k_scan23(
    const int* __restrict__ excl, const int* __restrict__ partials,
    int* __restrict__ offsets, int* __restrict__ cursor, int N) {
    __shared__ int sacc[256];
    int bid = blockIdx.x, t = threadIdx.x;
    int s = 0;
    for (int j = t; j < bid; j += 256) s += partials[j];
    sacc[t] = s; __syncthreads();
#pragma unroll
    for (int o = 128; o > 0; o >>= 1) {
        if (t < o) sacc[t] += sacc[t + o];
        __syncthreads();
    }
    int boff = sacc[0];
    int i = bid * 256 + t;
    if (i < N) {
        int o = excl[i] + boff;
        offsets[i] = o; cursor[i] = o;
    }
    if (t == 0 && bid == gridDim.x - 1) offsets[N] = boff + partials[bid];
}

// ---------------------------------------------------------------------------
// Fused scatter + logits: 8 lanes per edge (h = lane&7). Lane 0 claims the
// csr slot via atomic cursor, broadcasts pos; all lanes compute talking-heads
// logits directly into logits[pos], mpc[pos].
__global__ __launch_bounds__(256) void k_scatter_logits(
    const int* __restrict__ edge_dst, const int* __restrict__ mult,
    int* __restrict__ cursor, const int* __restrict__ mp,
    const float* __restrict__ P, const float* __restrict__ Wth,
    float* __restrict__ logits, int4* __restrict__ mpc, int E) {
    int e = blockIdx.x * 32 + (threadIdx.x >> 3);
    if (e >= E) return;
    int h = threadIdx.x & 7;
    int d = edge_dst[e];
    if (mult[d] == 0) return;
    int pos = 0;
    if (h == 0) pos = atomicAdd(&cursor[d], 1);
    int gbase = threadIdx.x & ~7;
    pos = __shfl(pos, gbase);
    int4 rows = *(const int4*)(mp + (size_t)e * 4);
    float s = P[(size_t)rows.x * 16 + h] + P[(size_t)rows.w * 16 + h]
            + P[(size_t)rows.y * 16 + 8 + h] + P[(size_t)rows.z * 16 + 8 + h];
    float l = 0.f;
#pragma unroll
    for (int j = 0; j < 8; ++j) {
        float sj = __shfl(s, gbase + j);
        l += Wth[h * 8 + j] * sj;
    }
    l = l > 0.f ? l : 0.01f * l;
    logits[(size_t)pos * 8 + h] = l;
    if (h == 0) mpc[pos] = rows;
}

// ---------------------------------------------------------------------------
// Per flagged node: single-pass ONLINE softmax + aggregation from Ybf.
// One wave per node, lane = d. 2-edge unroll to overlap L3 gather latency.
__global__ __launch_bounds__(256) void k_node_agg(
    const unsigned short* __restrict__ Ybf, const float* __restrict__ logits,
    const int4* __restrict__ mpc, const int* __restrict__ offsets,
    const int* __restrict__ mult, const float* __restrict__ Wg,
    unsigned short* __restrict__ nftb, float* __restrict__ gate_part, int N) {
    int n = blockIdx.x * 4 + (threadIdx.x >> 6);
    int lane = threadIdx.x & 63;
    if (n >= N) return;
    int m = mult[n];
    if (m == 0) return;
    int beg = offsets[n], end = offsets[n + 1];

    float mx[8], den[8], acc[8];
#pragma unroll
    for (int h = 0; h < 8; ++h) { mx[h] = -1e30f; den[h] = 0.f; acc[h] = 0.f; }

#define OSM_STEP(H, LV, EDV)                                       \
    {                                                              \
        float nm = fmaxf(mx[H], (LV));                             \
        float cr = __expf(mx[H] - nm);                             \
        float w  = __expf((LV) - nm);                              \
        den[H] = den[H] * cr + w;                                  \
        acc[H] = acc[H] * cr + w * (EDV);                          \
        mx[H] = nm;                                                \
    }
#define OSM8(L0, L1, EDV)                                          \
    OSM_STEP(0, (L0).x, EDV) OSM_STEP(1, (L0).y, EDV)              \
    OSM_STEP(2, (L0).z, EDV) OSM_STEP(3, (L0).w, EDV)              \
    OSM_STEP(4, (L1).x, EDV) OSM_STEP(5, (L1).y, EDV)              \
    OSM_STEP(6, (L1).z, EDV) OSM_STEP(7, (L1).w, EDV)

    int j = beg;
    for (; j + 2 <= end; j += 2) {
        const float4* lpa = (const float4*)(logits + (size_t)j * 8);
        const float4* lpb = (const float4*)(logits + (size_t)(j + 1) * 8);
        float4 a0 = lpa[0], a1 = lpa[1];
        float4 b0 = lpb[0], b1 = lpb[1];
        int4 ra = mpc[j];
        int4 rb = mpc[j + 1];
        float ed0 = bf2f(Ybf[(size_t)ra.x * 128 + lane])
                  + bf2f(Ybf[(size_t)ra.w * 128 + lane])
                  + bf2f(Ybf[(size_t)ra.y * 128 + 64 + lane])
                  + bf2f(Ybf[(size_t)ra.z * 128 + 64 + lane]);
        float ed1 = bf2f(Ybf[(size_t)rb.x * 128 + lane])
                  + bf2f(Ybf[(size_t)rb.w * 128 + lane])
                  + bf2f(Ybf[(size_t)rb.y * 128 + 64 + lane])
                  + bf2f(Ybf[(size_t)rb.z * 128 + 64 + lane]);
        OSM8(a0, a1, ed0)
        OSM8(b0, b1, ed1)
    }
    if (j < end) {
        const float4* lpa = (const float4*)(logits + (size_t)j * 8);
        float4 a0 = lpa[0], a1 = lpa[1];
        int4 ra = mpc[j];
        float ed0 = bf2f(Ybf[(size_t)ra.x * 128 + lane])
                  + bf2f(Ybf[(size_t)ra.w * 128 + lane])
                  + bf2f(Ybf[(size_t)ra.y * 128 + 64 + lane])
                  + bf2f(Ybf[(size_t)ra.z * 128 + 64 + lane]);
        OSM8(a0, a1, ed0)
    }
#undef OSM8
#undef OSM_STEP

#pragma unroll
    for (int h = 0; h < 8; ++h) {
        float r = (end > beg) ? 1.f / den[h] : 0.f;
        acc[h] *= r;
    }

    unsigned short* base = nftb + (size_t)n * 512;
#pragma unroll
    for (int h = 0; h < 8; ++h) base[h * 64 + lane] = f2bf(acc[h]);

    float wg = Wg[lane];
    float myg = 0.f;
#pragma unroll
    for (int h = 0; h < 8; ++h) {
        float p = acc[h] * wg;
#pragma unroll
        for (int o = 32; o > 0; o >>= 1) p += __shfl_xor(p, o);
        if (lane == h) myg = p;
    }
    if (lane < 8)
        atomicAdd(&gate_part[(blockIdx.x & 1023) * 8 + lane], (float)m * myg);
}

// gate[h] = sum(gate_part)/B + b_gate
__global__ __launch_bounds__(256) void k_gatefinal(
    const float* __restrict__ gate_part, const float* __restrict__ b_gate,
    float* __restrict__ gate, int B) {
    __shared__ float lds[256];
    int t = threadIdx.x;
    int h = t & 7, g = t >> 3;
    float s = 0.f;
    for (int b = g; b < 1024; b += 32) s += gate_part[b * 8 + h];
    lds[t] = s; __syncthreads();
    if (t < 8) {
        float tot = 0.f;
        for (int gg = 0; gg < 32; ++gg) tot += lds[gg * 8 + t];
        gate[t] = tot / (float)B + b_gate[0];
    }
}

// out[b, h*64+d] = nftb[batch_nodes[b]] * gate[h]  -- 16B/lane, NT stores
__global__ __launch_bounds__(256) void k_output(
    const unsigned short* __restrict__ nftb, const int* __restrict__ batch_nodes,
    const float* __restrict__ gate, float* __restrict__ out, int B) {
    int idx = blockIdx.x * 256 + threadIdx.x;
    int total = B * 64;
    if (idx >= total) return;
    int b = idx >> 6;
    int r = idx & 63;
    int h = r >> 3;
    int n = batch_nodes[b];
    u16x8 v = *(const u16x8*)(nftb + (size_t)n * 512 + r * 8);
    float g = gate[h];
    f32x4 o0, o1;
    o0[0] = bf2f(v[0]) * g; o0[1] = bf2f(v[1]) * g;
    o0[2] = bf2f(v[2]) * g; o0[3] = bf2f(v[3]) * g;
    o1[0] = bf2f(v[4]) * g; o1[1] = bf2f(v[5]) * g;
    o1[2] = bf2f(v[6]) * g; o1[3] = bf2f(v[7]) * g;
    f32x4* op = (f32x4*)(out + (size_t)idx * 8);
    __builtin_nontemporal_store(o0, op);
    __builtin_nontemporal_store(o1, op + 1);
}

// ---------------------------------------------------------------------------
extern "C" void kernel_launch(void* const* d_in, const int* in_sizes, int n_in,
                              void* d_out, int out_size, void* d_ws, size_t ws_size,
                              hipStream_t stream) {
    const int*   batch_nodes = (const int*)d_in[0];
    const int*   mp          = (const int*)d_in[1];
    const int*   edge_dst    = (const int*)d_in[2];
    const float* feat        = (const float*)d_in[3];
    const float* W_i         = (const float*)d_in[4];
    const float* W_p         = (const float*)d_in[5];
    const float* attn        = (const float*)d_in[6];
    const float* W_th        = (const float*)d_in[7];
    const float* W_gate      = (const float*)d_in[8];
    const float* b_gate      = (const float*)d_in[9];
    float* out = (float*)d_out;

    const int B = in_sizes[0];
    const int E = in_sizes[2];
    const int N = in_sizes[3] / 128;
    const int nb_scan = (N + 255) / 256;

    char* w = (char*)d_ws;
    auto alloc = [&](size_t bytes) -> void* {
        void* p = (void*)w;
        w += (bytes + 255) & ~(size_t)255;
        return p;
    };
    unsigned short* Whi = (unsigned short*)alloc(16384 * 2);
    unsigned short* Wlo = (unsigned short*)alloc(16384 * 2);
    unsigned short* Ybf = (unsigned short*)alloc((size_t)N * 128 * 2);   // 25.6 MB
    float* P            = (float*)alloc((size_t)N * 16 * 4);             // 6.4 MB
    float* logits       = (float*)alloc((size_t)E * 8 * 4);              // 9.6 MB
    int4*  mpc          = (int4*)alloc((size_t)E * 16);                  // 4.8 MB
    // contiguous zero region: mult | count | gate_part  (single memset)
    size_t zero_bytes   = (size_t)N * 4 + (size_t)N * 4 + 1024 * 8 * 4;
    int*   mult         = (int*)alloc(zero_bytes);
    int*   count        = mult + N;
    float* gate_part    = (float*)(count + N);
    int*   excl         = (int*)alloc((size_t)N * 4);
    int*   offsets      = (int*)alloc((size_t)(N + 1) * 4);
    int*   cursor       = (int*)alloc((size_t)N * 4);
    int*   partials     = (int*)alloc(512 * 4);
    unsigned short* nftb = (unsigned short*)alloc((size_t)N * 512 * 2);  // 102.4 MB
    float* gate         = (float*)alloc(256);

    hipMemsetAsync(mult, 0, zero_bytes, stream);

    int prep_work = (B > 16384) ? B : 16384;
    k_prep<<<(prep_work + 255) / 256, 256, 0, stream>>>(W_i, W_p, Whi, Wlo,
                                                        batch_nodes, mult, B);
    k_dense<<<(N + 63) / 64, 256, 0, stream>>>(feat, Whi, Wlo, attn,
                                               edge_dst, mult, count, Ybf, P, N, E);
    k_scan1<<<nb_scan, 256, 0, stream>>>(count, excl, partials, N);
    k_scan23<<<nb_scan, 256, 0, stream>>>(excl, partials, offsets, cursor, N);
    k_scatter_logits<<<(E + 31) / 32, 256, 0, stream>>>(edge_dst, mult, cursor,
                                                        mp, P, W_th, logits, mpc, E);
    k_node_agg<<<(N + 3) / 4, 256, 0, stream>>>(Ybf, logits, mpc, offsets, mult,
                                                W_gate, nftb, gate_part, N);
    k_gatefinal<<<1, 256, 0, stream>>>(gate_part, b_gate, gate, B);
    k_output<<<(B * 64 + 255) / 256, 256, 0, stream>>>(nftb, batch_nodes, gate, out, B);
}

// Round 5
// 314.528 us; speedup vs baseline: 2.9680x; 1.0615x over previous
//
#include <hip/hip_runtime.h>
#include <cstdint>
#include <cstddef>

// N=100000, E=300000, B=50000, L=4, D_EMB=128, D_HID=64, H=8. fp32 in/out.
// R7: node_agg VALU diet. rocprof R6b: node_agg 75.7us, VALUBusy 59%,
// HBM 13% -> VALU-bound on 16 exps/edge (online softmax) + rescale chain.
//  - per-(node,head) max now computed in k_scatter_logits via float-ordered
//    atomicMax on unsigned keys (monotonic encode; init 0 < all reals)
//  - node_agg single-pass plain softmax: 8 exps + 16 fma per edge, no
//    rescale chain, 2-edge unroll reverted
// Dispatches: 9 (memset, prep, dense(+hist), scan1, scan23, scatter_logits,
//                node_agg, gatefinal, output).

typedef __attribute__((ext_vector_type(8))) short bf16x8;
typedef __attribute__((ext_vector_type(4))) float f32x4;
typedef __attribute__((ext_vector_type(8))) unsigned short u16x8;

__device__ __forceinline__ unsigned short f2bf(float f) {
    unsigned u = __float_as_uint(f);
    unsigned r = u + 0x7fffu + ((u >> 16) & 1u);
    return (unsigned short)(r >> 16);
}
__device__ __forceinline__ float bf2f(unsigned short h) {
    return __uint_as_float((unsigned)h << 16);
}
// monotonic float<->unsigned order-preserving encode (for atomicMax)
__device__ __forceinline__ unsigned fenc(float f) {
    unsigned u = __float_as_uint(f);
    return (u & 0x80000000u) ? ~u : (u | 0x80000000u);
}
__device__ __forceinline__ float fdec(unsigned k) {
    unsigned u = (k & 0x80000000u) ? (k & 0x7fffffffu) : ~k;
    return __uint_as_float(u);
}

// ---------------------------------------------------------------------------
// Pack B = [Wi;Wp].T (K=128 x N=128) into MFMA B-frag order, split hi/lo bf16.
// Fused: batch-node multiplicity histogram.
__global__ __launch_bounds__(256) void k_prep(
    const float* __restrict__ Wi, const float* __restrict__ Wp,
    unsigned short* __restrict__ Whi, unsigned short* __restrict__ Wlo,
    const int* __restrict__ batch_nodes, int* __restrict__ mult, int B) {
    int t = blockIdx.x * 256 + threadIdx.x;
    if (t < B) atomicAdd(&mult[batch_nodes[t]], 1);
    if (t >= 16384) return;
    int j = t & 7, L = (t >> 3) & 63, c = (t >> 9) & 7, s = t >> 12;
    int k = s * 32 + (L >> 4) * 8 + j;
    int n = c * 16 + (L & 15);
    float v = (n < 64) ? Wi[n * 128 + k] : Wp[(n - 64) * 128 + k];
    unsigned short h = f2bf(v);
    Whi[t] = h;
    Wlo[t] = f2bf(v - bf2f(h));
}

// ---------------------------------------------------------------------------
// Dense GEMM: Ybf[M x 128] = feat[M x 128] @ B, split-bf16 (3 MFMA per tile).
// Prologue: edge histogram (needs mult). Epilogue: P[n,16] from fp32 acc.
__global__ __launch_bounds__(256) void k_dense(
    const float* __restrict__ feat, const unsigned short* __restrict__ Whi,
    const unsigned short* __restrict__ Wlo, const float* __restrict__ attn,
    const int* __restrict__ edge_dst, const int* __restrict__ mult,
    int* __restrict__ count, unsigned short* __restrict__ Ybf,
    float* __restrict__ P, int M, int E) {
    __shared__ unsigned short sBh[4096];
    __shared__ unsigned short sBl[4096];
    int t = threadIdx.x;

    // edge-hist prologue (grid covers E: (M+63)/64 * 256 >= 390k > 300k)
    {
        int e = blockIdx.x * 256 + t;
        if (e < E) {
            int d = edge_dst[e];
            if (mult[d] > 0) atomicAdd(&count[d], 1);
        }
    }

    int wave = t >> 6;
    int L = t & 63;
    int m = L & 15, q = L >> 4;
    int R0 = blockIdx.x * 64 + wave * 16;

    f32x4 acc[8];
#pragma unroll
    for (int c = 0; c < 8; ++c) acc[c] = (f32x4){0.f, 0.f, 0.f, 0.f};

    int rowc = R0 + m; if (rowc > M - 1) rowc = M - 1;
    const float* arow = feat + (size_t)rowc * 128;

    for (int s = 0; s < 4; ++s) {
        __syncthreads();   // protect previous iteration's LDS reads
        {
            bf16x8* shp = (bf16x8*)sBh;
            bf16x8* slp = (bf16x8*)sBl;
            const bf16x8* gh = (const bf16x8*)(Whi + s * 4096);
            const bf16x8* gl = (const bf16x8*)(Wlo + s * 4096);
            shp[t] = gh[t]; shp[t + 256] = gh[t + 256];
            slp[t] = gl[t]; slp[t + 256] = gl[t + 256];
        }
        __syncthreads();

        const float4* ap = (const float4*)(arow + s * 32 + q * 8);
        float4 a0 = ap[0], a1 = ap[1];
        float av[8] = {a0.x, a0.y, a0.z, a0.w, a1.x, a1.y, a1.z, a1.w};
        bf16x8 ahi, alo;
#pragma unroll
        for (int j = 0; j < 8; ++j) {
            unsigned short h = f2bf(av[j]);
            ahi[j] = (short)h;
            alo[j] = (short)f2bf(av[j] - bf2f(h));
        }
#pragma unroll
        for (int c = 0; c < 8; ++c) {
            const bf16x8 bh = *(const bf16x8*)(sBh + c * 512 + L * 8);
            const bf16x8 bl = *(const bf16x8*)(sBl + c * 512 + L * 8);
            acc[c] = __builtin_amdgcn_mfma_f32_16x16x32_bf16(ahi, bh, acc[c], 0, 0, 0);
            acc[c] = __builtin_amdgcn_mfma_f32_16x16x32_bf16(ahi, bl, acc[c], 0, 0, 0);
            acc[c] = __builtin_amdgcn_mfma_f32_16x16x32_bf16(alo, bh, acc[c], 0, 0, 0);
        }
    }
    // C/D layout: col = lane&15 (=m), row = (lane>>4)*4 + reg (=q*4+r)
#pragma unroll
    for (int c = 0; c < 8; ++c) {
#pragma unroll
        for (int r = 0; r < 4; ++r) {
            int row = R0 + q * 4 + r;
            if (row < M) Ybf[(size_t)row * 128 + c * 16 + m] = f2bf(acc[c][r]);
        }
    }
    // P epilogue: P[row,i] = Yi[row].attn_i, P[row,8+i] = Yp[row].attn_i.
#pragma unroll
    for (int i = 0; i < 8; ++i) {
        float a0 = attn[i * 64 + m];
        float a1 = attn[i * 64 + 16 + m];
        float a2 = attn[i * 64 + 32 + m];
        float a3 = attn[i * 64 + 48 + m];
#pragma unroll
        for (int r = 0; r < 4; ++r) {
            int row = R0 + q * 4 + r;
            float pi = acc[0][r] * a0 + acc[1][r] * a1 + acc[2][r] * a2 + acc[3][r] * a3;
            float pp = acc[4][r] * a0 + acc[5][r] * a1 + acc[6][r] * a2 + acc[7][r] * a3;
#pragma unroll
            for (int o = 1; o < 16; o <<= 1) {
                pi += __shfl_xor(pi, o);
                pp += __shfl_xor(pp, o);
            }
            if (row < M) {
                if (m == i)     P[(size_t)row * 16 + i] = pi;
                if (m == i + 8) P[(size_t)row * 16 + 8 + i] = pp;
            }
        }
    }
}

// ---------------------------------------------------------------------------
// per-block exclusive scan of count + block partial sums
__global__ __launch_bounds__(256) void k_scan1(
    const int* __restrict__ count, int* __restrict__ excl, int* __restrict__ partials, int N) {
    __shared__ int lds[256];
    int t = threadIdx.x, i = blockIdx.x * 256 + t;
    int c = (i < N) ? count[i] : 0;
    lds[t] = c; __syncthreads();
    for (int o = 1; o < 256; o <<= 1) {
        int v = (t >= o) ? lds[t - o] : 0;
        __syncthreads(); lds[t] += v; __syncthreads();
    }
    if (i < N) excl[i] = lds[t] - c;
    if (t == 255) partials[blockIdx.x] = lds[255];
}

// merged scan2+scan3
__global__ __launch_bounds__(256) void k_scan23(
    const int* __restrict__ excl, const int* __restrict__ partials,
    int* __restrict__ offsets, int* __restrict__ cursor, int N) {
    __shared__ int sacc[256];
    int bid = blockIdx.x, t = threadIdx.x;
    int s = 0;
    for (int j = t; j < bid; j += 256) s += partials[j];
    sacc[t] = s; __syncthreads();
#pragma unroll
    for (int o = 128; o > 0; o >>= 1) {
        if (t < o) sacc[t] += sacc[t + o];
        __syncthreads();
    }
    int boff = sacc[0];
    int i = bid * 256 + t;
    if (i < N) {
        int o = excl[i] + boff;
        offsets[i] = o; cursor[i] = o;
    }
    if (t == 0 && bid == gridDim.x - 1) offsets[N] = boff + partials[bid];
}

// ---------------------------------------------------------------------------
// Fused scatter + logits + per-(node,head) max (float-ordered atomicMax).
// 8 lanes per edge (h = lane&7).
__global__ __launch_bounds__(256) void k_scatter_logits(
    const int* __restrict__ edge_dst, const int* __restrict__ mult,
    int* __restrict__ cursor, const int* __restrict__ mp,
    const float* __restrict__ P, const float* __restrict__ Wth,
    float* __restrict__ logits, int4* __restrict__ mpc,
    unsigned* __restrict__ mxkey, int E) {
    int e = blockIdx.x * 32 + (threadIdx.x >> 3);
    if (e >= E) return;
    int h = threadIdx.x & 7;
    int d = edge_dst[e];
    if (mult[d] == 0) return;
    int pos = 0;
    if (h == 0) pos = atomicAdd(&cursor[d], 1);
    int gbase = threadIdx.x & ~7;
    pos = __shfl(pos, gbase);
    int4 rows = *(const int4*)(mp + (size_t)e * 4);
    float s = P[(size_t)rows.x * 16 + h] + P[(size_t)rows.w * 16 + h]
            + P[(size_t)rows.y * 16 + 8 + h] + P[(size_t)rows.z * 16 + 8 + h];
    float l = 0.f;
#pragma unroll
    for (int j = 0; j < 8; ++j) {
        float sj = __shfl(s, gbase + j);
        l += Wth[h * 8 + j] * sj;
    }
    l = l > 0.f ? l : 0.01f * l;
    logits[(size_t)pos * 8 + h] = l;
    atomicMax(&mxkey[(size_t)d * 8 + h], fenc(l));
    if (h == 0) mpc[pos] = rows;
}

// ---------------------------------------------------------------------------
// Per flagged node: single-pass plain softmax (max precomputed in mxkey) +
// aggregation from Ybf. One wave per node, lane = d. 8 exps/edge.
__global__ __launch_bounds__(256) void k_node_agg(
    const unsigned short* __restrict__ Ybf, const float* __restrict__ logits,
    const int4* __restrict__ mpc, const int* __restrict__ offsets,
    const int* __restrict__ mult, const unsigned* __restrict__ mxkey,
    const float* __restrict__ Wg,
    unsigned short* __restrict__ nftb, float* __restrict__ gate_part, int N) {
    int n = blockIdx.x * 4 + (threadIdx.x >> 6);
    int lane = threadIdx.x & 63;
    if (n >= N) return;
    int m = mult[n];
    if (m == 0) return;
    int beg = offsets[n], end = offsets[n + 1];

    float mx[8], den[8], acc[8];
#pragma unroll
    for (int h = 0; h < 8; ++h) {
        mx[h] = fdec(mxkey[(size_t)n * 8 + h]);
        den[h] = 0.f; acc[h] = 0.f;
    }

    for (int j = beg; j < end; ++j) {
        const float4* lp = (const float4*)(logits + (size_t)j * 8);
        float4 l0 = lp[0], l1 = lp[1];
        int4 rows = mpc[j];
        float ed = bf2f(Ybf[(size_t)rows.x * 128 + lane])
                 + bf2f(Ybf[(size_t)rows.w * 128 + lane])
                 + bf2f(Ybf[(size_t)rows.y * 128 + 64 + lane])
                 + bf2f(Ybf[(size_t)rows.z * 128 + 64 + lane]);
        float w0 = __expf(l0.x - mx[0]), w1 = __expf(l0.y - mx[1]);
        float w2 = __expf(l0.z - mx[2]), w3 = __expf(l0.w - mx[3]);
        float w4 = __expf(l1.x - mx[4]), w5 = __expf(l1.y - mx[5]);
        float w6 = __expf(l1.z - mx[6]), w7 = __expf(l1.w - mx[7]);
        den[0] += w0; den[1] += w1; den[2] += w2; den[3] += w3;
        den[4] += w4; den[5] += w5; den[6] += w6; den[7] += w7;
        acc[0] += w0 * ed; acc[1] += w1 * ed; acc[2] += w2 * ed; acc[3] += w3 * ed;
        acc[4] += w4 * ed; acc[5] += w5 * ed; acc[6] += w6 * ed; acc[7] += w7 * ed;
    }

#pragma unroll
    for (int h = 0; h < 8; ++h) {
        float r = (end > beg) ? 1.f / den[h] : 0.f;
        acc[h] *= r;
    }

    unsigned short* base = nftb + (size_t)n * 512;
#pragma unroll
    for (int h = 0; h < 8; ++h) base[h * 64 + lane] = f2bf(acc[h]);

    float wg = Wg[lane];
    float myg = 0.f;
#pragma unroll
    for (int h = 0; h < 8; ++h) {
        float p = acc[h] * wg;
#pragma unroll
        for (int o = 32; o > 0; o >>= 1) p += __shfl_xor(p, o);
        if (lane == h) myg = p;
    }
    if (lane < 8)
        atomicAdd(&gate_part[(blockIdx.x & 1023) * 8 + lane], (float)m * myg);
}

// gate[h] = sum(gate_part)/B + b_gate
__global__ __launch_bounds__(256) void k_gatefinal(
    const float* __restrict__ gate_part, const float* __restrict__ b_gate,
    float* __restrict__ gate, int B) {
    __shared__ float lds[256];
    int t = threadIdx.x;
    int h = t & 7, g = t >> 3;
    float s = 0.f;
    for (int b = g; b < 1024; b += 32) s += gate_part[b * 8 + h];
    lds[t] = s; __syncthreads();
    if (t < 8) {
        float tot = 0.f;
        for (int gg = 0; gg < 32; ++gg) tot += lds[gg * 8 + t];
        gate[t] = tot / (float)B + b_gate[0];
    }
}

// out[b, h*64+d] = nftb[batch_nodes[b]] * gate[h]  -- 16B/lane, NT stores
__global__ __launch_bounds__(256) void k_output(
    const unsigned short* __restrict__ nftb, const int* __restrict__ batch_nodes,
    const float* __restrict__ gate, float* __restrict__ out, int B) {
    int idx = blockIdx.x * 256 + threadIdx.x;
    int total = B * 64;
    if (idx >= total) return;
    int b = idx >> 6;
    int r = idx & 63;
    int h = r >> 3;
    int n = batch_nodes[b];
    u16x8 v = *(const u16x8*)(nftb + (size_t)n * 512 + r * 8);
    float g = gate[h];
    f32x4 o0, o1;
    o0[0] = bf2f(v[0]) * g; o0[1] = bf2f(v[1]) * g;
    o0[2] = bf2f(v[2]) * g; o0[3] = bf2f(v[3]) * g;
    o1[0] = bf2f(v[4]) * g; o1[1] = bf2f(v[5]) * g;
    o1[2] = bf2f(v[6]) * g; o1[3] = bf2f(v[7]) * g;
    f32x4* op = (f32x4*)(out + (size_t)idx * 8);
    __builtin_nontemporal_store(o0, op);
    __builtin_nontemporal_store(o1, op + 1);
}

// ---------------------------------------------------------------------------
extern "C" void kernel_launch(void* const* d_in, const int* in_sizes, int n_in,
                              void* d_out, int out_size, void* d_ws, size_t ws_size,
                              hipStream_t stream) {
    const int*   batch_nodes = (const int*)d_in[0];
    const int*   mp          = (const int*)d_in[1];
    const int*   edge_dst    = (const int*)d_in[2];
    const float* feat        = (const float*)d_in[3];
    const float* W_i         = (const float*)d_in[4];
    const float* W_p         = (const float*)d_in[5];
    const float* attn        = (const float*)d_in[6];
    const float* W_th        = (const float*)d_in[7];
    const float* W_gate      = (const float*)d_in[8];
    const float* b_gate      = (const float*)d_in[9];
    float* out = (float*)d_out;

    const int B = in_sizes[0];
    const int E = in_sizes[2];
    const int N = in_sizes[3] / 128;
    const int nb_scan = (N + 255) / 256;

    char* w = (char*)d_ws;
    auto alloc = [&](size_t bytes) -> void* {
        void* p = (void*)w;
        w += (bytes + 255) & ~(size_t)255;
        return p;
    };
    unsigned short* Whi = (unsigned short*)alloc(16384 * 2);
    unsigned short* Wlo = (unsigned short*)alloc(16384 * 2);
    unsigned short* Ybf = (unsigned short*)alloc((size_t)N * 128 * 2);   // 25.6 MB
    float* P            = (float*)alloc((size_t)N * 16 * 4);             // 6.4 MB
    float* logits       = (float*)alloc((size_t)E * 8 * 4);              // 9.6 MB
    int4*  mpc          = (int4*)alloc((size_t)E * 16);                  // 4.8 MB
    // contiguous zero region: mult | count | gate_part | mxkey (single memset)
    size_t zero_bytes   = (size_t)N * 4 + (size_t)N * 4 + 1024 * 8 * 4
                        + (size_t)N * 8 * 4;
    int*   mult         = (int*)alloc(zero_bytes);
    int*   count        = mult + N;
    float* gate_part    = (float*)(count + N);
    unsigned* mxkey     = (unsigned*)(gate_part + 8192);
    int*   excl         = (int*)alloc((size_t)N * 4);
    int*   offsets      = (int*)alloc((size_t)(N + 1) * 4);
    int*   cursor       = (int*)alloc((size_t)N * 4);
    int*   partials     = (int*)alloc(512 * 4);
    unsigned short* nftb = (unsigned short*)alloc((size_t)N * 512 * 2);  // 102.4 MB
    float* gate         = (float*)alloc(256);

    hipMemsetAsync(mult, 0, zero_bytes, stream);

    int prep_work = (B > 16384) ? B : 16384;
    k_prep<<<(prep_work + 255) / 256, 256, 0, stream>>>(W_i, W_p, Whi, Wlo,
                                                        batch_nodes, mult, B);
    k_dense<<<(N + 63) / 64, 256, 0, stream>>>(feat, Whi, Wlo, attn,
                                               edge_dst, mult, count, Ybf, P, N, E);
    k_scan1<<<nb_scan, 256, 0, stream>>>(count, excl, partials, N);
    k_scan23<<<nb_scan, 256, 0, stream>>>(excl, partials, offsets, cursor, N);
    k_scatter_logits<<<(E + 31) / 32, 256, 0, stream>>>(edge_dst, mult, cursor,
                                                        mp, P, W_th, logits, mpc,
                                                        mxkey, E);
    k_node_agg<<<(N + 3) / 4, 256, 0, stream>>>(Ybf, logits, mpc, offsets, mult,
                                                mxkey, W_gate, nftb, gate_part, N);
    k_gatefinal<<<1, 256, 0, stream>>>(gate_part, b_gate, gate, B);
    k_output<<<(B * 64 + 255) / 256, 256, 0, stream>>>(nftb, batch_nodes, gate, out, B);
}